// Round 10
// baseline (274.198 us; speedup 1.0000x reference)
//
#include <hip/hip_runtime.h>
#include <hip/hip_cooperative_groups.h>
#include <math.h>

namespace cg = cooperative_groups;

#define NN   8192
#define NB   4
#define NE   262144
#define EMB  64
#define HID  512
#define NOUT 64
#define DMAX 256          // table covers deg in [0, DMAX); others go special path
#define SPEC_FLAG (1 << 30)
#define SLICES 32         // 8192 edges per slice; per-slice deg counts fit u16
#define HBLK (NB * SLICES)            // 128 histogram blocks
#define HWORDS (NN / 2)               // 4096 packed u32 per slice histogram
#define GRID 512

// ---------------- block-level evaluator (256 threads = 4 waves, one job) ----------------
__device__ __forceinline__ void eval_block(
    float dg, float c0, float c1, float c2, float c3,
    const float* __restrict__ u, const float* __restrict__ b1,
    const float* __restrict__ ln_g, const float* __restrict__ ln_b,
    const float* __restrict__ w2t4, const float* __restrict__ b2,
    float* __restrict__ dst,
    float* __restrict__ g, float* __restrict__ pacc, float* __restrict__ red)
{
    int tid = threadIdx.x, lane = tid & 63, wid = tid >> 6;

    int h1i = tid + 256;
    float h0 = dg * u[tid] + c0 * u[512 + tid] + c1 * u[1024 + tid]
             + c2 * u[1536 + tid] + c3 * u[2048 + tid] + b1[tid];
    float h1 = dg * u[h1i] + c0 * u[512 + h1i] + c1 * u[1024 + h1i]
             + c2 * u[1536 + h1i] + c3 * u[2048 + h1i] + b1[h1i];

    float s = h0 + h1, ss = h0 * h0 + h1 * h1;
    #pragma unroll
    for (int d2 = 1; d2 < 64; d2 <<= 1) {
        s  += __shfl_xor(s,  d2, 64);
        ss += __shfl_xor(ss, d2, 64);
    }
    if (lane == 0) { red[wid] = s; red[4 + wid] = ss; }
    __syncthreads();
    float S  = red[0] + red[1] + red[2] + red[3];
    float SS = red[4] + red[5] + red[6] + red[7];
    float mu  = S * (1.0f / 512.0f);
    float var = SS * (1.0f / 512.0f) - mu * mu;
    float rs  = rsqrtf(var + 1e-5f);

    float x0 = (h0 - mu) * rs * ln_g[tid] + ln_b[tid];
    g[tid]  = 0.5f * x0 * (1.0f + erff(x0 * 0.70710678118654752f));
    float x1 = (h1 - mu) * rs * ln_g[h1i] + ln_b[h1i];
    g[h1i]  = 0.5f * x1 * (1.0f + erff(x1 * 0.70710678118654752f));
    __syncthreads();

    const float4* W2 = (const float4*)w2t4;
    int h4b = wid * 32;
    float a0 = 0.f, a1 = 0.f;
    #pragma unroll 8
    for (int k = 0; k < 32; k += 2) {
        float4 w0  = W2[(h4b + k) * 64 + lane];
        float4 g0  = *(const float4*)(g + (h4b + k) * 4);        // broadcast
        float4 w1v = W2[(h4b + k + 1) * 64 + lane];
        float4 g1  = *(const float4*)(g + (h4b + k + 1) * 4);    // broadcast
        a0 += w0.x * g0.x + w0.y * g0.y + w0.z * g0.z + w0.w * g0.w;
        a1 += w1v.x * g1.x + w1v.y * g1.y + w1v.z * g1.z + w1v.w * g1.w;
    }
    pacc[wid * 64 + lane] = a0 + a1;
    __syncthreads();
    if (tid < 64)
        dst[tid] = pacc[tid] + pacc[64 + tid] + pacc[128 + tid] + pacc[192 + tid] + b2[tid];
    __syncthreads();                                             // LDS safe for next job
}

// ---------------- fused cooperative kernel ----------------
// P0: zero cnt/nspec  | P1: hist + u + w2t4 prep | P2: deg+classify + table | P3: copy + specials
__global__ __launch_bounds__(256) void fused_kernel(
    const int* __restrict__ ei, const int* __restrict__ pert,
    const float* __restrict__ proj_w, const float* __restrict__ proj_b,
    const float* __restrict__ w1, const float* __restrict__ b1,
    const float* __restrict__ ln_g, const float* __restrict__ ln_b,
    const float* __restrict__ w2, const float* __restrict__ b2,
    int* __restrict__ deg, int* __restrict__ cnt,
    int* __restrict__ nspec, int* __restrict__ spec,
    float* __restrict__ u, float* __restrict__ w2t4,
    float* __restrict__ table, unsigned int* __restrict__ hist_g,
    float* __restrict__ out)
{
    cg::grid_group grid = cg::this_grid();
    __shared__ unsigned int hist[HWORDS];            // 16 KB
    __shared__ float pb[EMB];
    __shared__ float pw[EMB * 4];
    __shared__ float g[HID];
    __shared__ float pacc[4 * 64];
    __shared__ float red[8];
    int blk = blockIdx.x, tid = threadIdx.x;

    // ---- P0: zero cnt (131072 = GRID*256 exactly) + nspec ----
    cnt[blk * 256 + tid] = 0;
    if (blk == 0 && tid == 0) *nspec = 0;
    grid.sync();

    // ---- P1 ----
    if (blk < HBLK) {
        int b = blk >> 5, s = blk & (SLICES - 1);
        #pragma unroll
        for (int k = 0; k < 4; ++k)
            *(uint4*)(hist + (k * 256 + tid) * 4) = make_uint4(0, 0, 0, 0);
        __syncthreads();

        int p0 = pert[0], p1 = pert[1], p2 = pert[2], p3 = pert[3];
        const int* src = ei + (size_t)b * 2 * NE + s * (NE / SLICES);
        const int* dst = src + NE;
        int base = b * NN;
        #pragma unroll
        for (int k = 0; k < 8; ++k) {                // 8 int4 = 32 edges / thread
            int4 sv = ((const int4*)src)[k * 256 + tid];
            int4 dv = ((const int4*)dst)[k * 256 + tid];
            atomicAdd(&hist[sv.x >> 1], 1u << ((sv.x & 1) << 4));
            atomicAdd(&hist[sv.y >> 1], 1u << ((sv.y & 1) << 4));
            atomicAdd(&hist[sv.z >> 1], 1u << ((sv.z & 1) << 4));
            atomicAdd(&hist[sv.w >> 1], 1u << ((sv.w & 1) << 4));
            if (dv.x == p0) atomicAdd(&cnt[(base + sv.x) * 4 + 0], 1);
            if (dv.x == p1) atomicAdd(&cnt[(base + sv.x) * 4 + 1], 1);
            if (dv.x == p2) atomicAdd(&cnt[(base + sv.x) * 4 + 2], 1);
            if (dv.x == p3) atomicAdd(&cnt[(base + sv.x) * 4 + 3], 1);
            if (dv.y == p0) atomicAdd(&cnt[(base + sv.y) * 4 + 0], 1);
            if (dv.y == p1) atomicAdd(&cnt[(base + sv.y) * 4 + 1], 1);
            if (dv.y == p2) atomicAdd(&cnt[(base + sv.y) * 4 + 2], 1);
            if (dv.y == p3) atomicAdd(&cnt[(base + sv.y) * 4 + 3], 1);
            if (dv.z == p0) atomicAdd(&cnt[(base + sv.z) * 4 + 0], 1);
            if (dv.z == p1) atomicAdd(&cnt[(base + sv.z) * 4 + 1], 1);
            if (dv.z == p2) atomicAdd(&cnt[(base + sv.z) * 4 + 2], 1);
            if (dv.z == p3) atomicAdd(&cnt[(base + sv.z) * 4 + 3], 1);
            if (dv.w == p0) atomicAdd(&cnt[(base + sv.w) * 4 + 0], 1);
            if (dv.w == p1) atomicAdd(&cnt[(base + sv.w) * 4 + 1], 1);
            if (dv.w == p2) atomicAdd(&cnt[(base + sv.w) * 4 + 2], 1);
            if (dv.w == p3) atomicAdd(&cnt[(base + sv.w) * 4 + 3], 1);
        }
        __syncthreads();
        uint4* hg = (uint4*)(hist_g + (size_t)blk * HWORDS);
        #pragma unroll
        for (int k = 0; k < 4; ++k)
            hg[k * 256 + tid] = *(const uint4*)(hist + (k * 256 + tid) * 4);
    } else if (blk < HBLK + 2) {
        if (tid < EMB) pb[tid] = proj_b[tid];
        pw[tid] = proj_w[tid];
        __syncthreads();
        int hh = (blk - HBLK) * 256 + tid;           // 0..511
        const float4* row = (const float4*)(w1 + (size_t)hh * 256);
        float a0 = 0.f, a1 = 0.f, a2 = 0.f, a3 = 0.f, a4 = 0.f;
        #pragma unroll 8
        for (int e = 0; e < 64; ++e) {
            float4 v = row[e];
            float w = v.x + v.y + v.z + v.w;         // fold 4 hop copies (hop fastest)
            a0 += w * pb[e];
            a1 += w * pw[e * 4 + 0];
            a2 += w * pw[e * 4 + 1];
            a3 += w * pw[e * 4 + 2];
            a4 += w * pw[e * 4 + 3];
        }
        u[hh] = a0; u[512 + hh] = a1; u[1024 + hh] = a2; u[1536 + hh] = a3; u[2048 + hh] = a4;
    } else if (blk < HBLK + 34) {
        int gi = (blk - (HBLK + 2)) * 256 + tid;     // float4 index 0..8191
        int o = gi >> 7, h4 = gi & 127;
        float4 v = *(const float4*)(w2 + (size_t)o * HID + h4 * 4);
        *(float4*)(w2t4 + (size_t)(h4 * 64 + o) * 4) = v;
    }
    grid.sync();

    // ---- P2 ----
    if (blk < 128) {
        int gn = blk * 256 + tid;                    // 0 .. NB*NN-1
        int b = gn >> 13, n = gn & (NN - 1);
        const unsigned int* hb = hist_g + (size_t)b * SLICES * HWORDS + (n >> 1);
        int sh = (n & 1) << 4;
        int d = 0;
        #pragma unroll 8
        for (int s = 0; s < SLICES; ++s) d += (hb[s * HWORDS] >> sh) & 0xFFFFu;
        int4 c = *(const int4*)(cnt + gn * 4);
        bool sp = ((c.x | c.y | c.z | c.w) != 0) || (d >= DMAX);
        if (sp) {
            int i = atomicAdd(nspec, 1);
            spec[i] = gn;
            d |= SPEC_FLAG;
        }
        deg[gn] = d;
    } else if (blk < 384) {
        int i = blk - 128;                           // 0..255
        eval_block((float)i, 0.f, 0.f, 0.f, 0.f, u, b1, ln_g, ln_b, w2t4, b2,
                   table + (size_t)i * NOUT, g, pacc, red);
    }
    grid.sync();

    // ---- P3: table scatter (4 chunks / block) + special eval (grid-stride) ----
    #pragma unroll
    for (int k = 0; k < 4; ++k) {
        int t = (blk * 4 + k) * 256 + tid;           // 0 .. NB*NN*16-1 exactly
        int gn = t >> 4, q = t & 15;
        int d = deg[gn];
        if (!(d & SPEC_FLAG)) {                      // no early return (syncs follow)
            d = d < DMAX - 1 ? d : DMAX - 1;
            ((float4*)out)[(size_t)gn * 16 + q] = ((const float4*)table)[(size_t)d * 16 + q];
        }
    }
    int ns = *nspec;
    for (int i = blk; i < ns; i += GRID) {
        int gn = spec[i];
        float dg = (float)(deg[gn] & ~SPEC_FLAG);
        int4 c = *(const int4*)(cnt + gn * 4);
        eval_block(dg, (float)c.x, (float)c.y, (float)c.z, (float)c.w,
                   u, b1, ln_g, ln_b, w2t4, b2,
                   out + (size_t)gn * NOUT, g, pacc, red);
    }
}

// ---------------- launch ----------------
extern "C" void kernel_launch(void* const* d_in, const int* in_sizes, int n_in,
                              void* d_out, int out_size, void* d_ws, size_t ws_size,
                              hipStream_t stream) {
    const int*   ei     = (const int*)d_in[0];
    const int*   pert   = (const int*)d_in[1];
    const float* proj_w = (const float*)d_in[2];
    const float* proj_b = (const float*)d_in[3];
    const float* w1     = (const float*)d_in[4];
    const float* b1     = (const float*)d_in[5];
    const float* ln_g   = (const float*)d_in[6];
    const float* ln_b   = (const float*)d_in[7];
    const float* w2     = (const float*)d_in[8];
    const float* b2     = (const float*)d_in[9];
    float* out = (float*)d_out;

    // workspace layout
    char* ws = (char*)d_ws;
    int*          deg    = (int*)ws;                            // 32768
    int*          cnt    = deg + 32768;                         // 131072
    int*          nspec  = cnt + 131072;                        // 1
    int*          spec   = nspec + 1;                           // 32768
    float*        u      = (float*)(spec + 32768);              // 2560
    float*        w2t4   = u + 2560;                            // 32768
    float*        table  = w2t4 + 32768;                        // 16384
    unsigned int* hist_g = (unsigned int*)(table + 16384);      // 128*4096 u32 = 2 MB

    void* kargs[] = {
        (void*)&ei, (void*)&pert, (void*)&proj_w, (void*)&proj_b,
        (void*)&w1, (void*)&b1, (void*)&ln_g, (void*)&ln_b,
        (void*)&w2, (void*)&b2,
        (void*)&deg, (void*)&cnt, (void*)&nspec, (void*)&spec,
        (void*)&u, (void*)&w2t4, (void*)&table, (void*)&hist_g,
        (void*)&out
    };
    hipLaunchCooperativeKernel((void*)fused_kernel, dim3(GRID), dim3(256),
                               kargs, 0, stream);
}

// Round 12
// 105.355 us; speedup vs baseline: 2.6026x; 2.6026x over previous
//
#include <hip/hip_runtime.h>
#include <math.h>

#define NN   8192
#define NB   4
#define NE   262144
#define EMB  64
#define HID  512
#define NOUT 64
#define DMAX 256          // table covers deg in [0, DMAX); others go special path
#define SPEC_FLAG (1 << 30)
#define SLICES 32         // 8192 edges per slice; per-slice deg counts fit u16
#define HBLK (NB * SLICES)            // 128 histogram blocks
#define HWORDS (NN / 2)               // 4096 packed u32 per slice histogram

// ---------------- block-level evaluator (256 threads = 4 waves, one job) ----------------
// dst[0..63] = (GELU(LN(dg*u0 + c·u1..4 + b1)) @ w2^T + b2)
__device__ __forceinline__ void eval_block(
    float dg, float c0, float c1, float c2, float c3,
    const float* __restrict__ u, const float* __restrict__ b1,
    const float* __restrict__ ln_g, const float* __restrict__ ln_b,
    const float* __restrict__ w2t4, const float* __restrict__ b2,
    float* __restrict__ dst,
    float* __restrict__ g,       // [HID] LDS
    float* __restrict__ pacc,    // [4*64] LDS
    float* __restrict__ red)     // [8] LDS
{
    int tid = threadIdx.x, lane = tid & 63, wid = tid >> 6;

    // h for hh = tid and tid+256 (2 per thread)
    int h1i = tid + 256;
    float h0 = dg * u[tid] + c0 * u[512 + tid] + c1 * u[1024 + tid]
             + c2 * u[1536 + tid] + c3 * u[2048 + tid] + b1[tid];
    float h1 = dg * u[h1i] + c0 * u[512 + h1i] + c1 * u[1024 + h1i]
             + c2 * u[1536 + h1i] + c3 * u[2048 + h1i] + b1[h1i];

    float s = h0 + h1, ss = h0 * h0 + h1 * h1;
    #pragma unroll
    for (int d2 = 1; d2 < 64; d2 <<= 1) {
        s  += __shfl_xor(s,  d2, 64);
        ss += __shfl_xor(ss, d2, 64);
    }
    if (lane == 0) { red[wid] = s; red[4 + wid] = ss; }
    __syncthreads();
    float S  = red[0] + red[1] + red[2] + red[3];
    float SS = red[4] + red[5] + red[6] + red[7];
    float mu  = S * (1.0f / 512.0f);
    float var = SS * (1.0f / 512.0f) - mu * mu;
    float rs  = rsqrtf(var + 1e-5f);

    float x0 = (h0 - mu) * rs * ln_g[tid] + ln_b[tid];
    g[tid]  = 0.5f * x0 * (1.0f + erff(x0 * 0.70710678118654752f));
    float x1 = (h1 - mu) * rs * ln_g[h1i] + ln_b[h1i];
    g[h1i]  = 0.5f * x1 * (1.0f + erff(x1 * 0.70710678118654752f));
    __syncthreads();

    // matvec2: wave wid covers h4-chunks [wid*32, wid*32+32)
    const float4* W2 = (const float4*)w2t4;
    int h4b = wid * 32;
    float a0 = 0.f, a1 = 0.f;
    #pragma unroll 8
    for (int k = 0; k < 32; k += 2) {
        float4 w0  = W2[(h4b + k) * 64 + lane];
        float4 g0  = *(const float4*)(g + (h4b + k) * 4);        // broadcast
        float4 w1v = W2[(h4b + k + 1) * 64 + lane];
        float4 g1  = *(const float4*)(g + (h4b + k + 1) * 4);    // broadcast
        a0 += w0.x * g0.x + w0.y * g0.y + w0.z * g0.z + w0.w * g0.w;
        a1 += w1v.x * g1.x + w1v.y * g1.y + w1v.z * g1.z + w1v.w * g1.w;
    }
    pacc[wid * 64 + lane] = a0 + a1;
    __syncthreads();
    if (tid < 64)
        dst[tid] = pacc[tid] + pacc[64 + tid] + pacc[128 + tid] + pacc[192 + tid] + b2[tid];
    __syncthreads();                                             // LDS safe for next job
}

// ---------------- Kernel A: u16-packed LDS degree hist + cnt atomics + prep ----------------
// blocks 0..127   : graph b = blk>>5, slice s = blk&31 -> hist_g[blk][4096] (u16 pairs)
// blocks 128..129 : u[5][512] precompute
// blocks 130..161 : w2t4 lane-major transpose
__global__ __launch_bounds__(256) void phaseA_kernel(const int* __restrict__ ei,
                                                     const int* __restrict__ pert,
                                                     const float* __restrict__ w1,
                                                     const float* __restrict__ w2,
                                                     const float* __restrict__ proj_w,
                                                     const float* __restrict__ proj_b,
                                                     unsigned int* __restrict__ hist_g,
                                                     int* __restrict__ cnt,
                                                     float* __restrict__ u,
                                                     float* __restrict__ w2t4) {
    __shared__ unsigned int hist[HWORDS];            // 16 KB packed u16 counters
    __shared__ float pb[EMB];
    __shared__ float pw[EMB * 4];
    int blk = blockIdx.x, tid = threadIdx.x;

    if (blk < HBLK) {
        int b = blk >> 5, s = blk & (SLICES - 1);
        #pragma unroll
        for (int k = 0; k < 4; ++k)
            *(uint4*)(hist + (k * 256 + tid) * 4) = make_uint4(0, 0, 0, 0);
        __syncthreads();

        int p0 = pert[0], p1 = pert[1], p2 = pert[2], p3 = pert[3];
        const int* src = ei + (size_t)b * 2 * NE + s * (NE / SLICES);
        const int* dst = src + NE;
        int base = b * NN;
        #pragma unroll
        for (int k = 0; k < 8; ++k) {                // 8 int4 = 32 edges / thread
            int4 sv = ((const int4*)src)[k * 256 + tid];
            int4 dv = ((const int4*)dst)[k * 256 + tid];
            atomicAdd(&hist[sv.x >> 1], 1u << ((sv.x & 1) << 4));
            atomicAdd(&hist[sv.y >> 1], 1u << ((sv.y & 1) << 4));
            atomicAdd(&hist[sv.z >> 1], 1u << ((sv.z & 1) << 4));
            atomicAdd(&hist[sv.w >> 1], 1u << ((sv.w & 1) << 4));
            if (dv.x == p0) atomicAdd(&cnt[(base + sv.x) * 4 + 0], 1);
            if (dv.x == p1) atomicAdd(&cnt[(base + sv.x) * 4 + 1], 1);
            if (dv.x == p2) atomicAdd(&cnt[(base + sv.x) * 4 + 2], 1);
            if (dv.x == p3) atomicAdd(&cnt[(base + sv.x) * 4 + 3], 1);
            if (dv.y == p0) atomicAdd(&cnt[(base + sv.y) * 4 + 0], 1);
            if (dv.y == p1) atomicAdd(&cnt[(base + sv.y) * 4 + 1], 1);
            if (dv.y == p2) atomicAdd(&cnt[(base + sv.y) * 4 + 2], 1);
            if (dv.y == p3) atomicAdd(&cnt[(base + sv.y) * 4 + 3], 1);
            if (dv.z == p0) atomicAdd(&cnt[(base + sv.z) * 4 + 0], 1);
            if (dv.z == p1) atomicAdd(&cnt[(base + sv.z) * 4 + 1], 1);
            if (dv.z == p2) atomicAdd(&cnt[(base + sv.z) * 4 + 2], 1);
            if (dv.z == p3) atomicAdd(&cnt[(base + sv.z) * 4 + 3], 1);
            if (dv.w == p0) atomicAdd(&cnt[(base + sv.w) * 4 + 0], 1);
            if (dv.w == p1) atomicAdd(&cnt[(base + sv.w) * 4 + 1], 1);
            if (dv.w == p2) atomicAdd(&cnt[(base + sv.w) * 4 + 2], 1);
            if (dv.w == p3) atomicAdd(&cnt[(base + sv.w) * 4 + 3], 1);
        }
        __syncthreads();
        uint4* hg = (uint4*)(hist_g + (size_t)blk * HWORDS);
        #pragma unroll
        for (int k = 0; k < 4; ++k)
            hg[k * 256 + tid] = *(const uint4*)(hist + (k * 256 + tid) * 4);
    } else if (blk < HBLK + 2) {
        if (tid < EMB) pb[tid] = proj_b[tid];
        pw[tid] = proj_w[tid];
        __syncthreads();
        int hh = (blk - HBLK) * 256 + tid;           // 0..511
        const float4* row = (const float4*)(w1 + (size_t)hh * 256);
        float a0 = 0.f, a1 = 0.f, a2 = 0.f, a3 = 0.f, a4 = 0.f;
        #pragma unroll 8
        for (int e = 0; e < 64; ++e) {
            float4 v = row[e];
            float w = v.x + v.y + v.z + v.w;         // fold 4 hop copies (hop fastest)
            a0 += w * pb[e];
            a1 += w * pw[e * 4 + 0];
            a2 += w * pw[e * 4 + 1];
            a3 += w * pw[e * 4 + 2];
            a4 += w * pw[e * 4 + 3];
        }
        u[hh] = a0; u[512 + hh] = a1; u[1024 + hh] = a2; u[1536 + hh] = a3; u[2048 + hh] = a4;
    } else {
        int g = (blk - (HBLK + 2)) * 256 + tid;      // float4 index 0..8191
        int o = g >> 7, h4 = g & 127;
        float4 v = *(const float4*)(w2 + (size_t)o * HID + h4 * 4);
        *(float4*)(w2t4 + (size_t)(h4 * 64 + o) * 4) = v;
    }
}

// ---------------- Kernel B: reduce hist -> deg + classify, AND table (1 job/block) ------
// blocks 0..127  : per-node degree reduce + special classification
// blocks 128..383: table entry i = blk-128 (block-level eval)
__global__ __launch_bounds__(256) void phaseB_kernel(
    const unsigned int* __restrict__ hist_g, const int* __restrict__ cnt,
    int* __restrict__ deg, int* __restrict__ nspec, int* __restrict__ spec,
    const float* __restrict__ u, const float* __restrict__ b1,
    const float* __restrict__ ln_g, const float* __restrict__ ln_b,
    const float* __restrict__ w2t4, const float* __restrict__ b2,
    float* __restrict__ table)
{
    __shared__ float g[HID];
    __shared__ float pacc[4 * 64];
    __shared__ float red[8];
    int blk = blockIdx.x, tid = threadIdx.x;
    if (blk < 128) {
        int gn = blk * 256 + tid;                    // 0 .. NB*NN-1
        int b = gn >> 13, n = gn & (NN - 1);
        const unsigned int* hb = hist_g + (size_t)b * SLICES * HWORDS + (n >> 1);
        int sh = (n & 1) << 4;
        int d = 0;
        #pragma unroll 8
        for (int s = 0; s < SLICES; ++s) d += (hb[s * HWORDS] >> sh) & 0xFFFFu;
        int4 c = *(const int4*)(cnt + gn * 4);
        bool sp = ((c.x | c.y | c.z | c.w) != 0) || (d >= DMAX);
        if (sp) {
            int i = atomicAdd(nspec, 1);
            spec[i] = gn;
            d |= SPEC_FLAG;
        }
        deg[gn] = d;
    } else {
        int i = blk - 128;                           // 0..255
        eval_block((float)i, 0.f, 0.f, 0.f, 0.f, u, b1, ln_g, ln_b, w2t4, b2,
                   table + (size_t)i * NOUT, g, pacc, red);
    }
}

// ---------------- Kernel C: table scatter + special-node eval (1 job/block) ----------------
// blocks 0..2047   : copy table rows to all non-special nodes
// blocks 2048..2559: exact eval for special nodes (grid-stride)
__global__ __launch_bounds__(256) void phaseC_kernel(
    const int* __restrict__ nspec, const int* __restrict__ spec,
    const int* __restrict__ deg, const int* __restrict__ cnt,
    const float* __restrict__ u, const float* __restrict__ b1,
    const float* __restrict__ ln_g, const float* __restrict__ ln_b,
    const float* __restrict__ w2t4, const float* __restrict__ b2,
    const float* __restrict__ table, float* __restrict__ out)
{
    __shared__ float g[HID];
    __shared__ float pacc[4 * 64];
    __shared__ float red[8];
    int blk = blockIdx.x, tid = threadIdx.x;
    if (blk < 2048) {
        int t = blk * 256 + tid;                     // 0 .. NB*NN*16-1
        int gn = t >> 4, q = t & 15;
        int d = deg[gn];
        if (d & SPEC_FLAG) return;                   // eval writes this row directly
        d = d < DMAX - 1 ? d : DMAX - 1;
        ((float4*)out)[(size_t)gn * 16 + q] = ((const float4*)table)[(size_t)d * 16 + q];
    } else {
        int ns = *nspec;
        for (int i = blk - 2048; i < ns; i += 512) {
            int gn = spec[i];
            float dg = (float)(deg[gn] & ~SPEC_FLAG);
            int4 c = *(const int4*)(cnt + gn * 4);
            eval_block(dg, (float)c.x, (float)c.y, (float)c.z, (float)c.w,
                       u, b1, ln_g, ln_b, w2t4, b2,
                       out + (size_t)gn * NOUT, g, pacc, red);
        }
    }
}

// ---------------- launch ----------------
extern "C" void kernel_launch(void* const* d_in, const int* in_sizes, int n_in,
                              void* d_out, int out_size, void* d_ws, size_t ws_size,
                              hipStream_t stream) {
    const int*   ei     = (const int*)d_in[0];
    const int*   pert   = (const int*)d_in[1];
    const float* proj_w = (const float*)d_in[2];
    const float* proj_b = (const float*)d_in[3];
    const float* w1     = (const float*)d_in[4];
    const float* b1     = (const float*)d_in[5];
    const float* ln_g   = (const float*)d_in[6];
    const float* ln_b   = (const float*)d_in[7];
    const float* w2     = (const float*)d_in[8];
    const float* b2     = (const float*)d_in[9];
    float* out = (float*)d_out;

    // workspace layout
    char* ws = (char*)d_ws;
    int*          deg    = (int*)ws;                            // 32768
    int*          cnt    = deg + 32768;                         // 131072 (zeroed w/ nspec)
    int*          nspec  = cnt + 131072;                        // 1
    int*          spec   = nspec + 1;                           // 32768
    float*        u      = (float*)(spec + 32768);              // 2560
    float*        w2t4   = u + 2560;                            // 32768
    float*        table  = w2t4 + 32768;                        // 16384
    unsigned int* hist_g = (unsigned int*)(table + 16384);      // 128*4096 u32 = 2 MB

    hipMemsetAsync(cnt, 0, (131072 + 1) * 4, stream);           // cnt + nspec

    phaseA_kernel<<<HBLK + 34, 256, 0, stream>>>(ei, pert, w1, w2, proj_w, proj_b,
                                                 hist_g, cnt, u, w2t4);
    phaseB_kernel<<<384, 256, 0, stream>>>(hist_g, cnt, deg, nspec, spec,
                                           u, b1, ln_g, ln_b, w2t4, b2, table);
    phaseC_kernel<<<2560, 256, 0, stream>>>(nspec, spec, deg, cnt,
                                            u, b1, ln_g, ln_b, w2t4, b2, table, out);
}